// Round 9
// baseline (411.258 us; speedup 1.0000x reference)
//
#include <hip/hip_runtime.h>
#include <hip/hip_fp16.h>
#include <stdint.h>

// Problem constants (B=4, N=2048, F=256, H=4, C=64)
#define NNODE 2048

typedef _Float16 half8 __attribute__((ext_vector_type(8)));
typedef __fp16   fp16x2 __attribute__((ext_vector_type(2)));
typedef float    f32x16 __attribute__((ext_vector_type(16)));

__device__ __forceinline__ f32x16 zero16() {
    f32x16 z;
    #pragma unroll
    for (int i = 0; i < 16; ++i) z[i] = 0.f;
    return z;
}

// ---------------------------------------------------------------------------
// Pack adj (int32 0/1, [B][N][N]) into bitmask words.
// ---------------------------------------------------------------------------
__global__ __launch_bounds__(256) void pack_adj(const int* __restrict__ adj,
                                                unsigned long long* __restrict__ adjp) {
    int gid = blockIdx.x * 256 + threadIdx.x;
    unsigned long long m = __ballot(adj[gid] != 0);
    if ((threadIdx.x & 63) == 0) adjp[gid >> 6] = m;
}

// ---------------------------------------------------------------------------
// x fp32 [8192][256] -> xhi/xlo fp16 split. 4 floats/thread.
// ---------------------------------------------------------------------------
__global__ __launch_bounds__(256) void split_x(const float* __restrict__ x,
                                               __half* __restrict__ xhi,
                                               __half* __restrict__ xlo) {
    size_t gid = (size_t)blockIdx.x * 256 + threadIdx.x;
    float4 v = *reinterpret_cast<const float4*>(x + gid * 4);
    float vv[4] = {v.x, v.y, v.z, v.w};
    union { __half h[4]; uint2 u; } ph, pl;
    #pragma unroll
    for (int j = 0; j < 4; ++j) {
        __half hv = __float2half(vv[j]);
        ph.h[j] = hv;
        pl.h[j] = __float2half(vv[j] - __half2float(hv));
    }
    *reinterpret_cast<uint2*>(xhi + gid * 4) = ph.u;
    *reinterpret_cast<uint2*>(xlo + gid * 4) = pl.u;
}

// ---------------------------------------------------------------------------
// 6 weight matrices [256][256] fp32 -> wth/wtl [6][n][k] fp16 split TRANSPOSED
// ---------------------------------------------------------------------------
__global__ __launch_bounds__(256) void split_w(
    const float* __restrict__ W0, const float* __restrict__ W1, const float* __restrict__ W2,
    const float* __restrict__ W3, const float* __restrict__ W4, const float* __restrict__ W5,
    __half* __restrict__ wth, __half* __restrict__ wtl)
{
    __shared__ float T[64][65];
    const int which = blockIdx.y;
    const float* __restrict__ W = (which == 0) ? W0 : (which == 1) ? W1 : (which == 2) ? W2
                                 : (which == 3) ? W3 : (which == 4) ? W4 : W5;
    const int kx = (blockIdx.x & 3) * 64, nx = (blockIdx.x >> 2) * 64;
    const int t = threadIdx.x;
    #pragma unroll
    for (int p = 0; p < 4; ++p) {
        int id = p * 256 + t;
        int r = id >> 4, c4 = (id & 15) * 4;
        float4 v4 = *reinterpret_cast<const float4*>(W + (size_t)(kx + r) * 256 + nx + c4);
        T[r][c4 + 0] = v4.x; T[r][c4 + 1] = v4.y; T[r][c4 + 2] = v4.z; T[r][c4 + 3] = v4.w;
    }
    __syncthreads();
    const int n = t >> 2, kc = (t & 3) * 16;
    union { __half h[16]; uint4 u[2]; } hs, ls;
    #pragma unroll
    for (int i = 0; i < 16; ++i) {
        float v = T[kc + i][n];
        __half hv = __float2half(v);
        hs.h[i] = hv;
        ls.h[i] = __float2half(v - __half2float(hv));
    }
    size_t dst = ((size_t)(which * 256) + nx + n) * 256 + kx + kc;
    *reinterpret_cast<uint4*>(&wth[dst])     = hs.u[0];
    *reinterpret_cast<uint4*>(&wth[dst + 8]) = hs.u[1];
    *reinterpret_cast<uint4*>(&wtl[dst])     = ls.u[0];
    *reinterpret_cast<uint4*>(&wtl[dst + 8]) = ls.u[1];
}

// ---------------------------------------------------------------------------
// QKV GEMM on MFMA (split fp16, 3-term).
// Outputs: Q [bh][n][64] split (x0.125), K frag-linear split,
//          V DIRECT frag-linear split fp16 [bh][m/16][c][m%16] (no fp32 pass).
// ---------------------------------------------------------------------------
__global__ __launch_bounds__(256) void qkv_gemm_mfma(
    const __half* __restrict__ xh, const __half* __restrict__ xl,
    const __half* __restrict__ wth, const __half* __restrict__ wtl, const int wbase,
    __half* __restrict__ Qhi, __half* __restrict__ Qlo,
    __half* __restrict__ Khi, __half* __restrict__ Klo,
    __half* __restrict__ vthi, __half* __restrict__ vtlo)
{
    const int row0 = blockIdx.x * 64;
    const int nblk = blockIdx.y;
    const int which = nblk >> 2;             // 0=q,1=k,2=v
    const int h = nblk & 3;
    const int tid = threadIdx.x;
    const int wave = tid >> 6, lane = tid & 63;
    const int lq = lane & 31, hh = lane >> 5;
    const int wm = wave >> 1, wn = wave & 1;

    const size_t woff = ((size_t)((wbase + which) * 256) + h * 64 + wn * 32 + lq) * 256 + 8 * hh;
    const __half* __restrict__ wt_h = wth + woff;
    const __half* __restrict__ wt_l = wtl + woff;
    const size_t xoff = (size_t)(row0 + 32 * wm + lq) * 256 + 8 * hh;
    const __half* __restrict__ xr_h = xh + xoff;
    const __half* __restrict__ xr_l = xl + xoff;

    f32x16 st = zero16();
    #pragma unroll 4
    for (int ks = 0; ks < 16; ++ks) {
        half8 ah = *reinterpret_cast<const half8*>(xr_h + ks * 16);
        half8 al = *reinterpret_cast<const half8*>(xr_l + ks * 16);
        half8 bh = *reinterpret_cast<const half8*>(wt_h + ks * 16);
        half8 bl = *reinterpret_cast<const half8*>(wt_l + ks * 16);
        st = __builtin_amdgcn_mfma_f32_32x32x16_f16(ah, bh, st, 0, 0, 0);
        st = __builtin_amdgcn_mfma_f32_32x32x16_f16(al, bh, st, 0, 0, 0);
        st = __builtin_amdgcn_mfma_f32_32x32x16_f16(ah, bl, st, 0, 0, 0);
    }

    const int c = wn * 32 + lq;              // feature col 0..63
    if (which == 2) {
        // V direct frag-linear: idx = (bh*128 + (n>>4))*1024 + c*16 + (n&15)
        #pragma unroll
        for (int i = 0; i < 4; ++i) {        // 4 chunks of 4 consecutive rows
            int rowb = row0 + 32 * wm + 8 * i + 4 * hh;
            int b = rowb >> 11, n = rowb & 2047;
            size_t dst = (((size_t)(b * 4 + h) * 128) + (n >> 4)) * 1024
                         + (size_t)c * 16 + (n & 15);
            union { __half h[4]; uint2 u; } ph, pl;
            #pragma unroll
            for (int j = 0; j < 4; ++j) {
                float v = st[4 * i + j];
                __half hv = __float2half(v);
                ph.h[j] = hv;
                pl.h[j] = __float2half(v - __half2float(hv));
            }
            *reinterpret_cast<uint2*>(&vthi[dst]) = ph.u;
            *reinterpret_cast<uint2*>(&vtlo[dst]) = pl.u;
        }
    } else if (which == 0) {
        #pragma unroll
        for (int r = 0; r < 16; ++r) {
            int row = row0 + 32 * wm + (r & 3) + 8 * (r >> 2) + 4 * hh;
            int b = row >> 11, n = row & 2047;
            size_t idx = ((size_t)(b * 4 + h) * 2048 + n) * 64 + c;
            float v = st[r] * 0.125f;        // fold 1/sqrt(64)
            __half hv = __float2half(v);
            Qhi[idx] = hv;
            Qlo[idx] = __float2half(v - __half2float(hv));
        }
    } else {
        // K frag-linear: [bh][m/32][c/16][m%32][c%16]
        #pragma unroll
        for (int r = 0; r < 16; ++r) {
            int row = row0 + 32 * wm + (r & 3) + 8 * (r >> 2) + 4 * hh;
            int b = row >> 11, n = row & 2047;
            size_t idx = (((size_t)(b * 4 + h) * 64 + (n >> 5)) * 4 + (c >> 4)) * 512
                         + (size_t)(n & 31) * 16 + (c & 15);
            float v = st[r];
            __half hv = __float2half(v);
            Khi[idx] = hv;
            Klo[idx] = __float2half(v - __half2float(hv));
        }
    }
}

// ---------------------------------------------------------------------------
// Fused masked flash attention on MFMA (split fp16, swapped QK^T).
// Grid: 1024 blocks x 256 threads. Block = (bh, 32 q-rows); wave w = m-chunk.
// K-hi double-buffered in regs (prefetch t+1 during softmax/PV of t).
// ---------------------------------------------------------------------------
__global__ __launch_bounds__(256, 4) void gat_attn(
    const __half* __restrict__ qhi, const __half* __restrict__ qlo,
    const __half* __restrict__ khi, const __half* __restrict__ klo,
    const __half* __restrict__ vthi, const __half* __restrict__ vtlo,
    const unsigned long long* __restrict__ adjp,
    const float* __restrict__ bias, float* __restrict__ out,
    __half* __restrict__ hhi, __half* __restrict__ hlo, const int mode)
{
    const int lid = (blockIdx.x & 7) * 128 + (blockIdx.x >> 3);
    const int bh = lid >> 6, qt = lid & 63;
    const int b = bh >> 2, h = bh & 3;
    const int tid = threadIdx.x;
    const int wave = tid >> 6;
    const int lane = tid & 63;
    const int lq = lane & 31;
    const int hh = lane >> 5;
    const int q0 = qt * 32;

    const size_t qkbase = (size_t)bh * 2048 * 64;

    // Q fragments (B-operand: col = lane&31 = q, k = 16*ks + 8*hh + e)
    half8 qfh[4], qfl[4];
    {
        const __half* qr_h = qhi + qkbase + (size_t)(q0 + lq) * 64 + 8 * hh;
        const __half* qr_l = qlo + qkbase + (size_t)(q0 + lq) * 64 + 8 * hh;
        #pragma unroll
        for (int ks = 0; ks < 4; ++ks) {
            qfh[ks] = *reinterpret_cast<const half8*>(qr_h + ks * 16);
            qfl[ks] = *reinterpret_cast<const half8*>(qr_l + ks * 16);
        }
    }

    f32x16 o0 = zero16(), o1 = zero16();
    float mrun = -1e30f, lrun = 0.f;

    const unsigned long long* __restrict__ wrow = adjp + (size_t)(b * 2048 + q0 + lq) * 32;
    const int mbase = wave * 512;
    const int klane = lq * 16 + 8 * hh;      // lane offset within a 2048-half K tile

    // preload K-hi tile 0
    half8 kA[4], kB[4];
    {
        const __half* kp = khi + ((size_t)(bh * 64) + (mbase >> 5)) * 2048 + klane;
        #pragma unroll
        for (int ks = 0; ks < 4; ++ks) kA[ks] = *reinterpret_cast<const half8*>(kp + ks * 512);
    }

    unsigned long long wm64 = 0;

    auto tile_body = [&](half8 (&khc)[4], half8 (&khn)[4], int tt) {
        const int mt = mbase + 32 * tt;

        if ((tt & 1) == 0) wm64 = wrow[mt >> 6];
        const unsigned int v32 = (unsigned int)(wm64 >> ((tt & 1) * 32));

        // K-lo loads for this tile (covered by the 8 kh-only MFMAs below)
        const __half* klp = klo + ((size_t)(bh * 64) + (mt >> 5)) * 2048 + klane;
        half8 klv[4];
        #pragma unroll
        for (int ks = 0; ks < 4; ++ks) klv[ks] = *reinterpret_cast<const half8*>(klp + ks * 512);

        // ---- scores S^T = K * Q^T: kh terms first (prefetched), kl last ----
        f32x16 st = zero16();
        __builtin_amdgcn_s_setprio(1);
        #pragma unroll
        for (int ks = 0; ks < 4; ++ks)
            st = __builtin_amdgcn_mfma_f32_32x32x16_f16(khc[ks], qfh[ks], st, 0, 0, 0);
        #pragma unroll
        for (int ks = 0; ks < 4; ++ks)
            st = __builtin_amdgcn_mfma_f32_32x32x16_f16(khc[ks], qfl[ks], st, 0, 0, 0);
        #pragma unroll
        for (int ks = 0; ks < 4; ++ks)
            st = __builtin_amdgcn_mfma_f32_32x32x16_f16(klv[ks], qfh[ks], st, 0, 0, 0);
        __builtin_amdgcn_s_setprio(0);

        // ---- prefetch K-hi for next tile (consumed next tile_body) ----
        {
            const int mtn = (tt < 15) ? mt + 32 : mbase;   // wrap: harmless re-read
            const __half* knp = khi + ((size_t)(bh * 64) + (mtn >> 5)) * 2048 + klane;
            #pragma unroll
            for (int ks = 0; ks < 4; ++ks) khn[ks] = *reinterpret_cast<const half8*>(knp + ks * 512);
        }

        // ---- V loads issued early (hide latency under softmax) ----
        const __half* vb_h = vthi + ((size_t)(bh * 128) + (mt >> 4)) * 1024 + klane;
        const __half* vb_l = vtlo + ((size_t)(bh * 128) + (mt >> 4)) * 1024 + klane;
        half8 va0h = *reinterpret_cast<const half8*>(vb_h);
        half8 vb0h = *reinterpret_cast<const half8*>(vb_h + 512);
        half8 va0l = *reinterpret_cast<const half8*>(vb_l);
        half8 vb0l = *reinterpret_cast<const half8*>(vb_l + 512);

        // ---- mask + online softmax ----
        const unsigned int w2 = v32 >> (4 * hh);
        const unsigned int bits = (w2 & 0xFu) | ((w2 >> 4) & 0xF0u)
                                | ((w2 >> 8) & 0xF00u) | ((w2 >> 12) & 0xF000u);
        float tv[16];
        #pragma unroll
        for (int i = 0; i < 16; ++i)
            tv[i] = ((bits >> i) & 1u) ? st[i] : -1e30f;
        // balanced max tree (max3-fusable)
        float a0 = fmaxf(fmaxf(tv[0], tv[1]), tv[2]);
        float a1 = fmaxf(fmaxf(tv[3], tv[4]), tv[5]);
        float a2 = fmaxf(fmaxf(tv[6], tv[7]), tv[8]);
        float a3 = fmaxf(fmaxf(tv[9], tv[10]), tv[11]);
        float a4 = fmaxf(fmaxf(tv[12], tv[13]), tv[14]);
        float pm = fmaxf(fmaxf(fmaxf(a0, a1), fmaxf(a2, a3)), fmaxf(a4, tv[15]));
        pm = fmaxf(pm, __shfl_xor(pm, 32, 64));
        if (!__all(pm <= mrun)) {
            float mnew = fmaxf(mrun, pm);
            float sf = __expf(mrun - mnew);
            mrun = mnew;
            lrun *= sf;
            o0 *= sf;
            o1 *= sf;
        }
        float e[16];
        #pragma unroll
        for (int i = 0; i < 16; ++i)
            e[i] = ((bits >> i) & 1u) ? __expf(tv[i] - mrun) : 0.f;
        float ps = (((e[0] + e[1]) + (e[2] + e[3])) + ((e[4] + e[5]) + (e[6] + e[7])))
                 + (((e[8] + e[9]) + (e[10] + e[11])) + ((e[12] + e[13]) + (e[14] + e[15])));
        ps += __shfl_xor(ps, 32, 64);
        lrun += ps;

        // ---- P -> split fp16 B-frags + PV ----
        half8 va1h, vb1h, va1l, vb1l;
        #pragma unroll
        for (int t2 = 0; t2 < 2; ++t2) {
            unsigned int Hp[4], Lp[4];
            #pragma unroll
            for (int p2 = 0; p2 < 4; ++p2) {
                float ea = e[8 * t2 + 2 * p2], eb = e[8 * t2 + 2 * p2 + 1];
                union { fp16x2 f; unsigned int u; } ch, cl;
                ch.f = __builtin_amdgcn_cvt_pkrtz(ea, eb);
                float fa = (float)ch.f[0], fb = (float)ch.f[1];
                cl.f = __builtin_amdgcn_cvt_pkrtz(ea - fa, eb - fb);
                Hp[p2] = ch.u; Lp[p2] = cl.u;
            }
            unsigned int hr1 = (unsigned)__shfl_xor((int)(hh ? Hp[0] : Hp[2]), 32, 64);
            unsigned int hr2 = (unsigned)__shfl_xor((int)(hh ? Hp[1] : Hp[3]), 32, 64);
            unsigned int lr1 = (unsigned)__shfl_xor((int)(hh ? Lp[0] : Lp[2]), 32, 64);
            unsigned int lr2 = (unsigned)__shfl_xor((int)(hh ? Lp[1] : Lp[3]), 32, 64);
            union { unsigned int u[4]; half8 hv; } Bh, Bl;
            Bh.u[0] = hh ? hr1 : Hp[0]; Bh.u[1] = hh ? hr2 : Hp[1];
            Bh.u[2] = hh ? Hp[2] : hr1; Bh.u[3] = hh ? Hp[3] : hr2;
            Bl.u[0] = hh ? lr1 : Lp[0]; Bl.u[1] = hh ? lr2 : Lp[1];
            Bl.u[2] = hh ? Lp[2] : lr1; Bl.u[3] = hh ? Lp[3] : lr2;

            if (t2 == 0) {
                va1h = *reinterpret_cast<const half8*>(vb_h + 1024);
                vb1h = *reinterpret_cast<const half8*>(vb_h + 1536);
                va1l = *reinterpret_cast<const half8*>(vb_l + 1024);
                vb1l = *reinterpret_cast<const half8*>(vb_l + 1536);
            }
            half8 vah  = t2 ? va1h : va0h;
            half8 val  = t2 ? va1l : va0l;
            half8 vbh2 = t2 ? vb1h : vb0h;
            half8 vbl2 = t2 ? vb1l : vb0l;

            __builtin_amdgcn_s_setprio(1);
            o0 = __builtin_amdgcn_mfma_f32_32x32x16_f16(vah, Bh.hv, o0, 0, 0, 0);
            o0 = __builtin_amdgcn_mfma_f32_32x32x16_f16(val, Bh.hv, o0, 0, 0, 0);
            o0 = __builtin_amdgcn_mfma_f32_32x32x16_f16(vah, Bl.hv, o0, 0, 0, 0);
            o1 = __builtin_amdgcn_mfma_f32_32x32x16_f16(vbh2, Bh.hv, o1, 0, 0, 0);
            o1 = __builtin_amdgcn_mfma_f32_32x32x16_f16(vbl2, Bh.hv, o1, 0, 0, 0);
            o1 = __builtin_amdgcn_mfma_f32_32x32x16_f16(vbh2, Bl.hv, o1, 0, 0, 0);
            __builtin_amdgcn_s_setprio(0);
        }
    };

    #pragma unroll 1
    for (int tt2 = 0; tt2 < 8; ++tt2) {
        tile_body(kA, kB, 2 * tt2);       // uses kA, prefetches into kB
        tile_body(kB, kA, 2 * tt2 + 1);   // uses kB, prefetches into kA
    }

    // ---- in-LDS merge of the 4 m-chunk partials ----
    __shared__ float OS[4][64][33];
    __shared__ float MS[4][32];
    __shared__ float LS[4][32];

    #pragma unroll
    for (int ct = 0; ct < 2; ++ct) {
        #pragma unroll
        for (int i = 0; i < 16; ++i) {
            int c = 32 * ct + (i & 3) + 8 * (i >> 2) + 4 * hh;
            OS[wave][c][lq] = ct ? o1[i] : o0[i];
        }
    }
    if (hh == 0) { MS[wave][lq] = mrun; LS[wave][lq] = lrun; }
    __syncthreads();

    const int q = tid >> 3, c8 = (tid & 7) * 8;
    float m0v = MS[0][q], m1v = MS[1][q], m2v = MS[2][q], m3v = MS[3][q];
    float M = fmaxf(fmaxf(m0v, m1v), fmaxf(m2v, m3v));
    float w0 = __expf(m0v - M), w1 = __expf(m1v - M), w2w = __expf(m2v - M), w3 = __expf(m3v - M);
    float L = LS[0][q] * w0 + LS[1][q] * w1 + LS[2][q] * w2w + LS[3][q] * w3;
    float inv = 1.f / (L + 1e-16f);
    float res[8];
    #pragma unroll
    for (int j = 0; j < 8; ++j) {
        int c = c8 + j;
        float o = OS[0][c][q] * w0 + OS[1][c][q] * w1 + OS[2][c][q] * w2w + OS[3][c][q] * w3;
        res[j] = o * inv + bias[h * 64 + c];
    }
    size_t oidx = ((size_t)(b * 2048) + q0 + q) * 256 + h * 64 + c8;
    if (mode == 0) {
        union { __half h[8]; uint4 u; } sh, sl;
        #pragma unroll
        for (int j = 0; j < 8; ++j) {
            float val = fmaxf(res[j], 0.f);   // relu
            __half hv = __float2half(val);
            sh.h[j] = hv;
            sl.h[j] = __float2half(val - __half2float(hv));
        }
        *reinterpret_cast<uint4*>(&hhi[oidx]) = sh.u;
        *reinterpret_cast<uint4*>(&hlo[oidx]) = sl.u;
    } else {
        *reinterpret_cast<float4*>(&out[oidx])     = make_float4(res[0], res[1], res[2], res[3]);
        *reinterpret_cast<float4*>(&out[oidx + 4]) = make_float4(res[4], res[5], res[6], res[7]);
    }
}

// ---------------------------------------------------------------------------
extern "C" void kernel_launch(void* const* d_in, const int* in_sizes, int n_in,
                              void* d_out, int out_size, void* d_ws, size_t ws_size,
                              hipStream_t stream) {
    const float* x   = (const float*)d_in[0];
    const int*   adj = (const int*)d_in[1];
    const float* Wq1 = (const float*)d_in[2];
    const float* Wk1 = (const float*)d_in[3];
    const float* Wv1 = (const float*)d_in[4];
    const float* b1  = (const float*)d_in[5];
    const float* Wq2 = (const float*)d_in[6];
    const float* Wk2 = (const float*)d_in[7];
    const float* Wv2 = (const float*)d_in[8];
    const float* b2  = (const float*)d_in[9];
    float* outp = (float*)d_out;

    // workspace layout (MB offsets), total 44MB
    char* ws = (char*)d_ws;
    unsigned long long* adjp = (unsigned long long*)ws;        //  0..2
    __half* xhi = (__half*)(ws + ( 2u << 20));                 //  2..6   (reused as hhi)
    __half* xlo = (__half*)(ws + ( 6u << 20));                 //  6..10  (reused as hlo)
    __half* wth = (__half*)(ws + (10u << 20));                 // 10..11 (768KB)
    __half* wtl = (__half*)(ws + (11u << 20));                 // 11..12
    __half* qhi = (__half*)(ws + (12u << 20));
    __half* qlo = (__half*)(ws + (16u << 20));
    __half* khi = (__half*)(ws + (20u << 20));
    __half* klo = (__half*)(ws + (24u << 20));
    __half* vthi= (__half*)(ws + (36u << 20));
    __half* vtlo= (__half*)(ws + (40u << 20));

    pack_adj<<<65536, 256, 0, stream>>>(adj, adjp);
    split_x<<<2048, 256, 0, stream>>>(x, xhi, xlo);
    split_w<<<dim3(16, 6), 256, 0, stream>>>(Wq1, Wk1, Wv1, Wq2, Wk2, Wv2, wth, wtl);

    qkv_gemm_mfma<<<dim3(128, 12), 256, 0, stream>>>(xhi, xlo, wth, wtl, 0,
                                                     qhi, qlo, khi, klo, vthi, vtlo);
    gat_attn<<<1024, 256, 0, stream>>>(qhi, qlo, khi, klo, vthi, vtlo, adjp, b1,
                                       outp, xhi, xlo, 0);

    qkv_gemm_mfma<<<dim3(128, 12), 256, 0, stream>>>(xhi, xlo, wth, wtl, 3,
                                                     qhi, qlo, khi, klo, vthi, vtlo);
    gat_attn<<<1024, 256, 0, stream>>>(qhi, qlo, khi, klo, vthi, vtlo, adjp, b2,
                                       outp, xhi, xlo, 1);
}

// Round 11
// 362.958 us; speedup vs baseline: 1.1331x; 1.1331x over previous
//
#include <hip/hip_runtime.h>
#include <hip/hip_fp16.h>
#include <stdint.h>

// Problem constants (B=4, N=2048, F=256, H=4, C=64)
#define NNODE 2048

typedef _Float16 half8 __attribute__((ext_vector_type(8)));
typedef __fp16   fp16x2 __attribute__((ext_vector_type(2)));
typedef float    f32x16 __attribute__((ext_vector_type(16)));

__device__ __forceinline__ f32x16 zero16() {
    f32x16 z;
    #pragma unroll
    for (int i = 0; i < 16; ++i) z[i] = 0.f;
    return z;
}

// ---------------------------------------------------------------------------
// Pack adj (int32 0/1, [B][N][N]) into bitmask words.
// ---------------------------------------------------------------------------
__global__ __launch_bounds__(256) void pack_adj(const int* __restrict__ adj,
                                                unsigned long long* __restrict__ adjp) {
    int gid = blockIdx.x * 256 + threadIdx.x;
    unsigned long long m = __ballot(adj[gid] != 0);
    if ((threadIdx.x & 63) == 0) adjp[gid >> 6] = m;
}

// ---------------------------------------------------------------------------
// x fp32 [8192][256] -> xhi/xlo fp16 split. 4 floats/thread.
// ---------------------------------------------------------------------------
__global__ __launch_bounds__(256) void split_x(const float* __restrict__ x,
                                               __half* __restrict__ xhi,
                                               __half* __restrict__ xlo) {
    size_t gid = (size_t)blockIdx.x * 256 + threadIdx.x;
    float4 v = *reinterpret_cast<const float4*>(x + gid * 4);
    float vv[4] = {v.x, v.y, v.z, v.w};
    union { __half h[4]; uint2 u; } ph, pl;
    #pragma unroll
    for (int j = 0; j < 4; ++j) {
        __half hv = __float2half(vv[j]);
        ph.h[j] = hv;
        pl.h[j] = __float2half(vv[j] - __half2float(hv));
    }
    *reinterpret_cast<uint2*>(xhi + gid * 4) = ph.u;
    *reinterpret_cast<uint2*>(xlo + gid * 4) = pl.u;
}

// ---------------------------------------------------------------------------
// 6 weight matrices [256][256] fp32 -> wth/wtl [6][n][k] fp16 split TRANSPOSED
// ---------------------------------------------------------------------------
__global__ __launch_bounds__(256) void split_w(
    const float* __restrict__ W0, const float* __restrict__ W1, const float* __restrict__ W2,
    const float* __restrict__ W3, const float* __restrict__ W4, const float* __restrict__ W5,
    __half* __restrict__ wth, __half* __restrict__ wtl)
{
    __shared__ float T[64][65];
    const int which = blockIdx.y;
    const float* __restrict__ W = (which == 0) ? W0 : (which == 1) ? W1 : (which == 2) ? W2
                                 : (which == 3) ? W3 : (which == 4) ? W4 : W5;
    const int kx = (blockIdx.x & 3) * 64, nx = (blockIdx.x >> 2) * 64;
    const int t = threadIdx.x;
    #pragma unroll
    for (int p = 0; p < 4; ++p) {
        int id = p * 256 + t;
        int r = id >> 4, c4 = (id & 15) * 4;
        float4 v4 = *reinterpret_cast<const float4*>(W + (size_t)(kx + r) * 256 + nx + c4);
        T[r][c4 + 0] = v4.x; T[r][c4 + 1] = v4.y; T[r][c4 + 2] = v4.z; T[r][c4 + 3] = v4.w;
    }
    __syncthreads();
    const int n = t >> 2, kc = (t & 3) * 16;
    union { __half h[16]; uint4 u[2]; } hs, ls;
    #pragma unroll
    for (int i = 0; i < 16; ++i) {
        float v = T[kc + i][n];
        __half hv = __float2half(v);
        hs.h[i] = hv;
        ls.h[i] = __float2half(v - __half2float(hv));
    }
    size_t dst = ((size_t)(which * 256) + nx + n) * 256 + kx + kc;
    *reinterpret_cast<uint4*>(&wth[dst])     = hs.u[0];
    *reinterpret_cast<uint4*>(&wth[dst + 8]) = hs.u[1];
    *reinterpret_cast<uint4*>(&wtl[dst])     = ls.u[0];
    *reinterpret_cast<uint4*>(&wtl[dst + 8]) = ls.u[1];
}

// ---------------------------------------------------------------------------
// QKV GEMM on MFMA (split fp16, 3-term).
// Outputs: Q [bh][n][64] split (x0.125), K frag-linear split,
//          V DIRECT frag-linear split fp16 [bh][m/16][c][m%16] (no fp32 pass).
// ---------------------------------------------------------------------------
__global__ __launch_bounds__(256) void qkv_gemm_mfma(
    const __half* __restrict__ xh, const __half* __restrict__ xl,
    const __half* __restrict__ wth, const __half* __restrict__ wtl, const int wbase,
    __half* __restrict__ Qhi, __half* __restrict__ Qlo,
    __half* __restrict__ Khi, __half* __restrict__ Klo,
    __half* __restrict__ vthi, __half* __restrict__ vtlo)
{
    const int row0 = blockIdx.x * 64;
    const int nblk = blockIdx.y;
    const int which = nblk >> 2;             // 0=q,1=k,2=v
    const int h = nblk & 3;
    const int tid = threadIdx.x;
    const int wave = tid >> 6, lane = tid & 63;
    const int lq = lane & 31, hh = lane >> 5;
    const int wm = wave >> 1, wn = wave & 1;

    const size_t woff = ((size_t)((wbase + which) * 256) + h * 64 + wn * 32 + lq) * 256 + 8 * hh;
    const __half* __restrict__ wt_h = wth + woff;
    const __half* __restrict__ wt_l = wtl + woff;
    const size_t xoff = (size_t)(row0 + 32 * wm + lq) * 256 + 8 * hh;
    const __half* __restrict__ xr_h = xh + xoff;
    const __half* __restrict__ xr_l = xl + xoff;

    f32x16 st = zero16();
    #pragma unroll 4
    for (int ks = 0; ks < 16; ++ks) {
        half8 ah = *reinterpret_cast<const half8*>(xr_h + ks * 16);
        half8 al = *reinterpret_cast<const half8*>(xr_l + ks * 16);
        half8 bh = *reinterpret_cast<const half8*>(wt_h + ks * 16);
        half8 bl = *reinterpret_cast<const half8*>(wt_l + ks * 16);
        st = __builtin_amdgcn_mfma_f32_32x32x16_f16(ah, bh, st, 0, 0, 0);
        st = __builtin_amdgcn_mfma_f32_32x32x16_f16(al, bh, st, 0, 0, 0);
        st = __builtin_amdgcn_mfma_f32_32x32x16_f16(ah, bl, st, 0, 0, 0);
    }

    const int c = wn * 32 + lq;              // feature col 0..63
    if (which == 2) {
        // V direct frag-linear: idx = (bh*128 + (n>>4))*1024 + c*16 + (n&15)
        #pragma unroll
        for (int i = 0; i < 4; ++i) {        // 4 chunks of 4 consecutive rows
            int rowb = row0 + 32 * wm + 8 * i + 4 * hh;
            int b = rowb >> 11, n = rowb & 2047;
            size_t dst = (((size_t)(b * 4 + h) * 128) + (n >> 4)) * 1024
                         + (size_t)c * 16 + (n & 15);
            union { __half h[4]; uint2 u; } ph, pl;
            #pragma unroll
            for (int j = 0; j < 4; ++j) {
                float v = st[4 * i + j];
                __half hv = __float2half(v);
                ph.h[j] = hv;
                pl.h[j] = __float2half(v - __half2float(hv));
            }
            *reinterpret_cast<uint2*>(&vthi[dst]) = ph.u;
            *reinterpret_cast<uint2*>(&vtlo[dst]) = pl.u;
        }
    } else if (which == 0) {
        #pragma unroll
        for (int r = 0; r < 16; ++r) {
            int row = row0 + 32 * wm + (r & 3) + 8 * (r >> 2) + 4 * hh;
            int b = row >> 11, n = row & 2047;
            size_t idx = ((size_t)(b * 4 + h) * 2048 + n) * 64 + c;
            float v = st[r] * 0.125f;        // fold 1/sqrt(64)
            __half hv = __float2half(v);
            Qhi[idx] = hv;
            Qlo[idx] = __float2half(v - __half2float(hv));
        }
    } else {
        // K frag-linear: [bh][m/32][c/16][m%32][c%16]
        #pragma unroll
        for (int r = 0; r < 16; ++r) {
            int row = row0 + 32 * wm + (r & 3) + 8 * (r >> 2) + 4 * hh;
            int b = row >> 11, n = row & 2047;
            size_t idx = (((size_t)(b * 4 + h) * 64 + (n >> 5)) * 4 + (c >> 4)) * 512
                         + (size_t)(n & 31) * 16 + (c & 15);
            float v = st[r];
            __half hv = __float2half(v);
            Khi[idx] = hv;
            Klo[idx] = __float2half(v - __half2float(hv));
        }
    }
}

// ---------------------------------------------------------------------------
// Fused masked flash attention on MFMA (split fp16, swapped QK^T).
// Grid: 1024 blocks x 256 threads. Block = (bh, 32 q-rows); wave w = m-chunk.
// K-hi double-buffered in regs. launch_bounds(256,2): VGPR cap 128, no spills
// (R9 lesson: (256,4) squeezed to 64 VGPR -> scratch spills, FETCH 14->77MB).
// ---------------------------------------------------------------------------
__global__ __launch_bounds__(256, 2) void gat_attn(
    const __half* __restrict__ qhi, const __half* __restrict__ qlo,
    const __half* __restrict__ khi, const __half* __restrict__ klo,
    const __half* __restrict__ vthi, const __half* __restrict__ vtlo,
    const unsigned long long* __restrict__ adjp,
    const float* __restrict__ bias, float* __restrict__ out,
    __half* __restrict__ hhi, __half* __restrict__ hlo, const int mode)
{
    const int lid = (blockIdx.x & 7) * 128 + (blockIdx.x >> 3);
    const int bh = lid >> 6, qt = lid & 63;
    const int b = bh >> 2, h = bh & 3;
    const int tid = threadIdx.x;
    const int wave = tid >> 6;
    const int lane = tid & 63;
    const int lq = lane & 31;
    const int hh = lane >> 5;
    const int q0 = qt * 32;

    const size_t qkbase = (size_t)bh * 2048 * 64;

    // Q fragments (B-operand: col = lane&31 = q, k = 16*ks + 8*hh + e)
    half8 qfh[4], qfl[4];
    {
        const __half* qr_h = qhi + qkbase + (size_t)(q0 + lq) * 64 + 8 * hh;
        const __half* qr_l = qlo + qkbase + (size_t)(q0 + lq) * 64 + 8 * hh;
        #pragma unroll
        for (int ks = 0; ks < 4; ++ks) {
            qfh[ks] = *reinterpret_cast<const half8*>(qr_h + ks * 16);
            qfl[ks] = *reinterpret_cast<const half8*>(qr_l + ks * 16);
        }
    }

    f32x16 o0 = zero16(), o1 = zero16();
    float mrun = -1e30f, lrun = 0.f;

    const unsigned long long* __restrict__ wrow = adjp + (size_t)(b * 2048 + q0 + lq) * 32;
    const int mbase = wave * 512;
    const int klane = lq * 16 + 8 * hh;      // lane offset within a 2048-half K tile

    // preload K-hi tile 0
    half8 kA[4], kB[4];
    {
        const __half* kp = khi + ((size_t)(bh * 64) + (mbase >> 5)) * 2048 + klane;
        #pragma unroll
        for (int ks = 0; ks < 4; ++ks) kA[ks] = *reinterpret_cast<const half8*>(kp + ks * 512);
    }

    unsigned long long wm64 = 0;

    auto tile_body = [&](half8 (&khc)[4], half8 (&khn)[4], int tt) {
        const int mt = mbase + 32 * tt;

        if ((tt & 1) == 0) wm64 = wrow[mt >> 6];
        const unsigned int v32 = (unsigned int)(wm64 >> ((tt & 1) * 32));

        // K-lo loads for this tile (covered by the 8 kh-only MFMAs below)
        const __half* klp = klo + ((size_t)(bh * 64) + (mt >> 5)) * 2048 + klane;
        half8 klv[4];
        #pragma unroll
        for (int ks = 0; ks < 4; ++ks) klv[ks] = *reinterpret_cast<const half8*>(klp + ks * 512);

        // ---- scores S^T = K * Q^T: kh terms first (prefetched), kl last ----
        f32x16 st = zero16();
        __builtin_amdgcn_s_setprio(1);
        #pragma unroll
        for (int ks = 0; ks < 4; ++ks)
            st = __builtin_amdgcn_mfma_f32_32x32x16_f16(khc[ks], qfh[ks], st, 0, 0, 0);
        #pragma unroll
        for (int ks = 0; ks < 4; ++ks)
            st = __builtin_amdgcn_mfma_f32_32x32x16_f16(khc[ks], qfl[ks], st, 0, 0, 0);
        #pragma unroll
        for (int ks = 0; ks < 4; ++ks)
            st = __builtin_amdgcn_mfma_f32_32x32x16_f16(klv[ks], qfh[ks], st, 0, 0, 0);
        __builtin_amdgcn_s_setprio(0);

        // ---- prefetch K-hi for next tile (consumed next tile_body) ----
        {
            const int mtn = (tt < 15) ? mt + 32 : mbase;   // wrap: harmless re-read
            const __half* knp = khi + ((size_t)(bh * 64) + (mtn >> 5)) * 2048 + klane;
            #pragma unroll
            for (int ks = 0; ks < 4; ++ks) khn[ks] = *reinterpret_cast<const half8*>(knp + ks * 512);
        }

        // ---- V loads issued early (hide latency under softmax) ----
        const __half* vb_h = vthi + ((size_t)(bh * 128) + (mt >> 4)) * 1024 + klane;
        const __half* vb_l = vtlo + ((size_t)(bh * 128) + (mt >> 4)) * 1024 + klane;
        half8 va0h = *reinterpret_cast<const half8*>(vb_h);
        half8 vb0h = *reinterpret_cast<const half8*>(vb_h + 512);
        half8 va0l = *reinterpret_cast<const half8*>(vb_l);
        half8 vb0l = *reinterpret_cast<const half8*>(vb_l + 512);

        // ---- mask + online softmax ----
        const unsigned int w2 = v32 >> (4 * hh);
        const unsigned int bits = (w2 & 0xFu) | ((w2 >> 4) & 0xF0u)
                                | ((w2 >> 8) & 0xF00u) | ((w2 >> 12) & 0xF000u);
        float tv[16];
        #pragma unroll
        for (int i = 0; i < 16; ++i)
            tv[i] = ((bits >> i) & 1u) ? st[i] : -1e30f;
        // balanced max tree (max3-fusable)
        float a0 = fmaxf(fmaxf(tv[0], tv[1]), tv[2]);
        float a1 = fmaxf(fmaxf(tv[3], tv[4]), tv[5]);
        float a2 = fmaxf(fmaxf(tv[6], tv[7]), tv[8]);
        float a3 = fmaxf(fmaxf(tv[9], tv[10]), tv[11]);
        float a4 = fmaxf(fmaxf(tv[12], tv[13]), tv[14]);
        float pm = fmaxf(fmaxf(fmaxf(a0, a1), fmaxf(a2, a3)), fmaxf(a4, tv[15]));
        pm = fmaxf(pm, __shfl_xor(pm, 32, 64));
        if (!__all(pm <= mrun)) {
            float mnew = fmaxf(mrun, pm);
            float sf = __expf(mrun - mnew);
            mrun = mnew;
            lrun *= sf;
            o0 *= sf;
            o1 *= sf;
        }
        float e[16];
        #pragma unroll
        for (int i = 0; i < 16; ++i)
            e[i] = ((bits >> i) & 1u) ? __expf(tv[i] - mrun) : 0.f;
        float ps = (((e[0] + e[1]) + (e[2] + e[3])) + ((e[4] + e[5]) + (e[6] + e[7])))
                 + (((e[8] + e[9]) + (e[10] + e[11])) + ((e[12] + e[13]) + (e[14] + e[15])));
        ps += __shfl_xor(ps, 32, 64);
        lrun += ps;

        // ---- P -> split fp16 B-frags + PV ----
        half8 va1h, vb1h, va1l, vb1l;
        #pragma unroll
        for (int t2 = 0; t2 < 2; ++t2) {
            unsigned int Hp[4], Lp[4];
            #pragma unroll
            for (int p2 = 0; p2 < 4; ++p2) {
                float ea = e[8 * t2 + 2 * p2], eb = e[8 * t2 + 2 * p2 + 1];
                union { fp16x2 f; unsigned int u; } ch, cl;
                ch.f = __builtin_amdgcn_cvt_pkrtz(ea, eb);
                float fa = (float)ch.f[0], fb = (float)ch.f[1];
                cl.f = __builtin_amdgcn_cvt_pkrtz(ea - fa, eb - fb);
                Hp[p2] = ch.u; Lp[p2] = cl.u;
            }
            unsigned int hr1 = (unsigned)__shfl_xor((int)(hh ? Hp[0] : Hp[2]), 32, 64);
            unsigned int hr2 = (unsigned)__shfl_xor((int)(hh ? Hp[1] : Hp[3]), 32, 64);
            unsigned int lr1 = (unsigned)__shfl_xor((int)(hh ? Lp[0] : Lp[2]), 32, 64);
            unsigned int lr2 = (unsigned)__shfl_xor((int)(hh ? Lp[1] : Lp[3]), 32, 64);
            union { unsigned int u[4]; half8 hv; } Bh, Bl;
            Bh.u[0] = hh ? hr1 : Hp[0]; Bh.u[1] = hh ? hr2 : Hp[1];
            Bh.u[2] = hh ? Hp[2] : hr1; Bh.u[3] = hh ? Hp[3] : hr2;
            Bl.u[0] = hh ? lr1 : Lp[0]; Bl.u[1] = hh ? lr2 : Lp[1];
            Bl.u[2] = hh ? Lp[2] : lr1; Bl.u[3] = hh ? Lp[3] : lr2;

            if (t2 == 0) {
                va1h = *reinterpret_cast<const half8*>(vb_h + 1024);
                vb1h = *reinterpret_cast<const half8*>(vb_h + 1536);
                va1l = *reinterpret_cast<const half8*>(vb_l + 1024);
                vb1l = *reinterpret_cast<const half8*>(vb_l + 1536);
            }
            half8 vah  = t2 ? va1h : va0h;
            half8 val  = t2 ? va1l : va0l;
            half8 vbh2 = t2 ? vb1h : vb0h;
            half8 vbl2 = t2 ? vb1l : vb0l;

            __builtin_amdgcn_s_setprio(1);
            o0 = __builtin_amdgcn_mfma_f32_32x32x16_f16(vah, Bh.hv, o0, 0, 0, 0);
            o0 = __builtin_amdgcn_mfma_f32_32x32x16_f16(val, Bh.hv, o0, 0, 0, 0);
            o0 = __builtin_amdgcn_mfma_f32_32x32x16_f16(vah, Bl.hv, o0, 0, 0, 0);
            o1 = __builtin_amdgcn_mfma_f32_32x32x16_f16(vbh2, Bh.hv, o1, 0, 0, 0);
            o1 = __builtin_amdgcn_mfma_f32_32x32x16_f16(vbl2, Bh.hv, o1, 0, 0, 0);
            o1 = __builtin_amdgcn_mfma_f32_32x32x16_f16(vbh2, Bl.hv, o1, 0, 0, 0);
            __builtin_amdgcn_s_setprio(0);
        }
    };

    #pragma unroll 1
    for (int tt2 = 0; tt2 < 8; ++tt2) {
        tile_body(kA, kB, 2 * tt2);       // uses kA, prefetches into kB
        tile_body(kB, kA, 2 * tt2 + 1);   // uses kB, prefetches into kA
    }

    // ---- in-LDS merge of the 4 m-chunk partials ----
    __shared__ float OS[4][64][33];
    __shared__ float MS[4][32];
    __shared__ float LS[4][32];

    #pragma unroll
    for (int ct = 0; ct < 2; ++ct) {
        #pragma unroll
        for (int i = 0; i < 16; ++i) {
            int c = 32 * ct + (i & 3) + 8 * (i >> 2) + 4 * hh;
            OS[wave][c][lq] = ct ? o1[i] : o0[i];
        }
    }
    if (hh == 0) { MS[wave][lq] = mrun; LS[wave][lq] = lrun; }
    __syncthreads();

    const int q = tid >> 3, c8 = (tid & 7) * 8;
    float m0v = MS[0][q], m1v = MS[1][q], m2v = MS[2][q], m3v = MS[3][q];
    float M = fmaxf(fmaxf(m0v, m1v), fmaxf(m2v, m3v));
    float w0 = __expf(m0v - M), w1 = __expf(m1v - M), w2w = __expf(m2v - M), w3 = __expf(m3v - M);
    float L = LS[0][q] * w0 + LS[1][q] * w1 + LS[2][q] * w2w + LS[3][q] * w3;
    float inv = 1.f / (L + 1e-16f);
    float res[8];
    #pragma unroll
    for (int j = 0; j < 8; ++j) {
        int c = c8 + j;
        float o = OS[0][c][q] * w0 + OS[1][c][q] * w1 + OS[2][c][q] * w2w + OS[3][c][q] * w3;
        res[j] = o * inv + bias[h * 64 + c];
    }
    size_t oidx = ((size_t)(b * 2048) + q0 + q) * 256 + h * 64 + c8;
    if (mode == 0) {
        union { __half h[8]; uint4 u; } sh, sl;
        #pragma unroll
        for (int j = 0; j < 8; ++j) {
            float val = fmaxf(res[j], 0.f);   // relu
            __half hv = __float2half(val);
            sh.h[j] = hv;
            sl.h[j] = __float2half(val - __half2float(hv));
        }
        *reinterpret_cast<uint4*>(&hhi[oidx]) = sh.u;
        *reinterpret_cast<uint4*>(&hlo[oidx]) = sl.u;
    } else {
        *reinterpret_cast<float4*>(&out[oidx])     = make_float4(res[0], res[1], res[2], res[3]);
        *reinterpret_cast<float4*>(&out[oidx + 4]) = make_float4(res[4], res[5], res[6], res[7]);
    }
}

// ---------------------------------------------------------------------------
extern "C" void kernel_launch(void* const* d_in, const int* in_sizes, int n_in,
                              void* d_out, int out_size, void* d_ws, size_t ws_size,
                              hipStream_t stream) {
    const float* x   = (const float*)d_in[0];
    const int*   adj = (const int*)d_in[1];
    const float* Wq1 = (const float*)d_in[2];
    const float* Wk1 = (const float*)d_in[3];
    const float* Wv1 = (const float*)d_in[4];
    const float* b1  = (const float*)d_in[5];
    const float* Wq2 = (const float*)d_in[6];
    const float* Wk2 = (const float*)d_in[7];
    const float* Wv2 = (const float*)d_in[8];
    const float* b2  = (const float*)d_in[9];
    float* outp = (float*)d_out;

    // workspace layout (MB offsets), total 44MB
    char* ws = (char*)d_ws;
    unsigned long long* adjp = (unsigned long long*)ws;        //  0..2
    __half* xhi = (__half*)(ws + ( 2u << 20));                 //  2..6   (reused as hhi)
    __half* xlo = (__half*)(ws + ( 6u << 20));                 //  6..10  (reused as hlo)
    __half* wth = (__half*)(ws + (10u << 20));                 // 10..11 (768KB)
    __half* wtl = (__half*)(ws + (11u << 20));                 // 11..12
    __half* qhi = (__half*)(ws + (12u << 20));
    __half* qlo = (__half*)(ws + (16u << 20));
    __half* khi = (__half*)(ws + (20u << 20));
    __half* klo = (__half*)(ws + (24u << 20));
    __half* vthi= (__half*)(ws + (36u << 20));
    __half* vtlo= (__half*)(ws + (40u << 20));

    pack_adj<<<65536, 256, 0, stream>>>(adj, adjp);
    split_x<<<2048, 256, 0, stream>>>(x, xhi, xlo);
    split_w<<<dim3(16, 6), 256, 0, stream>>>(Wq1, Wk1, Wv1, Wq2, Wk2, Wv2, wth, wtl);

    qkv_gemm_mfma<<<dim3(128, 12), 256, 0, stream>>>(xhi, xlo, wth, wtl, 0,
                                                     qhi, qlo, khi, klo, vthi, vtlo);
    gat_attn<<<1024, 256, 0, stream>>>(qhi, qlo, khi, klo, vthi, vtlo, adjp, b1,
                                       outp, xhi, xlo, 0);

    qkv_gemm_mfma<<<dim3(128, 12), 256, 0, stream>>>(xhi, xlo, wth, wtl, 3,
                                                     qhi, qlo, khi, klo, vthi, vtlo);
    gat_attn<<<1024, 256, 0, stream>>>(qhi, qlo, khi, klo, vthi, vtlo, adjp, b2,
                                       outp, xhi, xlo, 1);
}

// Round 12
// 308.052 us; speedup vs baseline: 1.3350x; 1.1782x over previous
//
#include <hip/hip_runtime.h>
#include <hip/hip_fp16.h>
#include <stdint.h>

// Problem constants (B=4, N=2048, F=256, H=4, C=64)
#define NNODE 2048

typedef _Float16 half8 __attribute__((ext_vector_type(8)));
typedef __fp16   fp16x2 __attribute__((ext_vector_type(2)));
typedef float    f32x16 __attribute__((ext_vector_type(16)));

__device__ __forceinline__ f32x16 zero16() {
    f32x16 z;
    #pragma unroll
    for (int i = 0; i < 16; ++i) z[i] = 0.f;
    return z;
}

// Frag-linear A/B layout (for 32x32x16 MFMA operands), logical (row,k):
//   idx = (row>>5)*8192 + (k>>4)*512 + (row&31)*16 + (k&15)
// -> a wave's fragment load (lane lq, half hh) is contiguous 2KB per instr.

// ---------------------------------------------------------------------------
// Pack adj (int32 0/1, [B][N][N]) into bitmask words.
// ---------------------------------------------------------------------------
__global__ __launch_bounds__(256) void pack_adj(const int* __restrict__ adj,
                                                unsigned long long* __restrict__ adjp) {
    int gid = blockIdx.x * 256 + threadIdx.x;
    unsigned long long m = __ballot(adj[gid] != 0);
    if ((threadIdx.x & 63) == 0) adjp[gid >> 6] = m;
}

// ---------------------------------------------------------------------------
// x fp32 [8192][256] -> xhi/xlo fp16 split, FRAG-LINEAR A layout.
// ---------------------------------------------------------------------------
__global__ __launch_bounds__(256) void split_x(const float* __restrict__ x,
                                               __half* __restrict__ xhi,
                                               __half* __restrict__ xlo) {
    size_t gid = (size_t)blockIdx.x * 256 + threadIdx.x;
    size_t p = gid * 4;
    int row = (int)(p >> 8), k = (int)(p & 255);
    float4 v = *reinterpret_cast<const float4*>(x + p);
    float vv[4] = {v.x, v.y, v.z, v.w};
    union { __half h[4]; uint2 u; } ph, pl;
    #pragma unroll
    for (int j = 0; j < 4; ++j) {
        __half hv = __float2half(vv[j]);
        ph.h[j] = hv;
        pl.h[j] = __float2half(vv[j] - __half2float(hv));
    }
    size_t dst = (size_t)(row >> 5) * 8192 + (size_t)(k >> 4) * 512
               + (size_t)(row & 31) * 16 + (k & 15);
    *reinterpret_cast<uint2*>(xhi + dst) = ph.u;
    *reinterpret_cast<uint2*>(xlo + dst) = pl.u;
}

// ---------------------------------------------------------------------------
// 6 weight matrices [256][256] fp32 -> wth/wtl fp16 split, transposed,
// FRAG-LINEAR B layout per matrix: idx = w*65536 + (n>>5)*8192 + (k>>4)*512
//                                        + (n&31)*16 + (k&15)
// ---------------------------------------------------------------------------
__global__ __launch_bounds__(256) void split_w(
    const float* __restrict__ W0, const float* __restrict__ W1, const float* __restrict__ W2,
    const float* __restrict__ W3, const float* __restrict__ W4, const float* __restrict__ W5,
    __half* __restrict__ wth, __half* __restrict__ wtl)
{
    __shared__ float T[64][65];
    const int which = blockIdx.y;
    const float* __restrict__ W = (which == 0) ? W0 : (which == 1) ? W1 : (which == 2) ? W2
                                 : (which == 3) ? W3 : (which == 4) ? W4 : W5;
    const int kx = (blockIdx.x & 3) * 64, nx = (blockIdx.x >> 2) * 64;
    const int t = threadIdx.x;
    #pragma unroll
    for (int p = 0; p < 4; ++p) {
        int id = p * 256 + t;
        int r = id >> 4, c4 = (id & 15) * 4;
        float4 v4 = *reinterpret_cast<const float4*>(W + (size_t)(kx + r) * 256 + nx + c4);
        T[r][c4 + 0] = v4.x; T[r][c4 + 1] = v4.y; T[r][c4 + 2] = v4.z; T[r][c4 + 3] = v4.w;
    }
    __syncthreads();
    const int n = t >> 2, kc = (t & 3) * 16;   // n: 0..63 within tile, kc: k-group base
    union { __half h[16]; uint4 u[2]; } hs, ls;
    #pragma unroll
    for (int i = 0; i < 16; ++i) {
        float v = T[kc + i][n];                // = W[kx+kc+i][nx+n]
        __half hv = __float2half(v);
        hs.h[i] = hv;
        ls.h[i] = __float2half(v - __half2float(hv));
    }
    const int N = nx + n, K = kx + kc;
    size_t dst = (size_t)which * 65536 + (size_t)(N >> 5) * 8192 + (size_t)(K >> 4) * 512
               + (size_t)(N & 31) * 16;
    *reinterpret_cast<uint4*>(&wth[dst])     = hs.u[0];
    *reinterpret_cast<uint4*>(&wth[dst + 8]) = hs.u[1];
    *reinterpret_cast<uint4*>(&wtl[dst])     = ls.u[0];
    *reinterpret_cast<uint4*>(&wtl[dst + 8]) = ls.u[1];
}

// ---------------------------------------------------------------------------
// QKV GEMM on MFMA (split fp16, 3-term), frag-linear A and B (coalesced loads).
// Outputs: Q [bh][n][64] split (x0.125), K frag-linear split,
//          V direct frag-linear split fp16 [bh][m/16][c][m%16].
// ---------------------------------------------------------------------------
__global__ __launch_bounds__(256) void qkv_gemm_mfma(
    const __half* __restrict__ xh, const __half* __restrict__ xl,
    const __half* __restrict__ wth, const __half* __restrict__ wtl, const int wbase,
    __half* __restrict__ Qhi, __half* __restrict__ Qlo,
    __half* __restrict__ Khi, __half* __restrict__ Klo,
    __half* __restrict__ vthi, __half* __restrict__ vtlo)
{
    const int row0 = blockIdx.x * 64;
    const int nblk = blockIdx.y;
    const int which = nblk >> 2;             // 0=q,1=k,2=v
    const int h = nblk & 3;
    const int tid = threadIdx.x;
    const int wave = tid >> 6, lane = tid & 63;
    const int lq = lane & 31, hh = lane >> 5;
    const int wm = wave >> 1, wn = wave & 1;

    // frag-linear bases: A rowtile = blockIdx.x*2+wm; B ntile = h*2+wn
    const size_t aoff = (size_t)(blockIdx.x * 2 + wm) * 8192 + lq * 16 + 8 * hh;
    const size_t boff = (size_t)(wbase + which) * 65536 + (size_t)(h * 2 + wn) * 8192
                      + lq * 16 + 8 * hh;
    const __half* __restrict__ xr_h = xh + aoff;
    const __half* __restrict__ xr_l = xl + aoff;
    const __half* __restrict__ wt_h = wth + boff;
    const __half* __restrict__ wt_l = wtl + boff;

    f32x16 st = zero16();
    #pragma unroll 4
    for (int ks = 0; ks < 16; ++ks) {
        half8 ah = *reinterpret_cast<const half8*>(xr_h + ks * 512);
        half8 al = *reinterpret_cast<const half8*>(xr_l + ks * 512);
        half8 bh = *reinterpret_cast<const half8*>(wt_h + ks * 512);
        half8 bl = *reinterpret_cast<const half8*>(wt_l + ks * 512);
        st = __builtin_amdgcn_mfma_f32_32x32x16_f16(ah, bh, st, 0, 0, 0);
        st = __builtin_amdgcn_mfma_f32_32x32x16_f16(al, bh, st, 0, 0, 0);
        st = __builtin_amdgcn_mfma_f32_32x32x16_f16(ah, bl, st, 0, 0, 0);
    }

    const int c = wn * 32 + lq;              // feature col 0..63
    if (which == 2) {
        // V direct frag-linear: idx = (bh*128 + (n>>4))*1024 + c*16 + (n&15)
        #pragma unroll
        for (int i = 0; i < 4; ++i) {
            int rowb = row0 + 32 * wm + 8 * i + 4 * hh;
            int b = rowb >> 11, n = rowb & 2047;
            size_t dst = (((size_t)(b * 4 + h) * 128) + (n >> 4)) * 1024
                         + (size_t)c * 16 + (n & 15);
            union { __half h[4]; uint2 u; } ph, pl;
            #pragma unroll
            for (int j = 0; j < 4; ++j) {
                float v = st[4 * i + j];
                __half hv = __float2half(v);
                ph.h[j] = hv;
                pl.h[j] = __float2half(v - __half2float(hv));
            }
            *reinterpret_cast<uint2*>(&vthi[dst]) = ph.u;
            *reinterpret_cast<uint2*>(&vtlo[dst]) = pl.u;
        }
    } else if (which == 0) {
        #pragma unroll
        for (int r = 0; r < 16; ++r) {
            int row = row0 + 32 * wm + (r & 3) + 8 * (r >> 2) + 4 * hh;
            int b = row >> 11, n = row & 2047;
            size_t idx = ((size_t)(b * 4 + h) * 2048 + n) * 64 + c;
            float v = st[r] * 0.125f;        // fold 1/sqrt(64)
            __half hv = __float2half(v);
            Qhi[idx] = hv;
            Qlo[idx] = __float2half(v - __half2float(hv));
        }
    } else {
        // K frag-linear: [bh][m/32][c/16][m%32][c%16]
        #pragma unroll
        for (int r = 0; r < 16; ++r) {
            int row = row0 + 32 * wm + (r & 3) + 8 * (r >> 2) + 4 * hh;
            int b = row >> 11, n = row & 2047;
            size_t idx = (((size_t)(b * 4 + h) * 64 + (n >> 5)) * 4 + (c >> 4)) * 512
                         + (size_t)(n & 31) * 16 + (c & 15);
            float v = st[r];
            __half hv = __float2half(v);
            Khi[idx] = hv;
            Klo[idx] = __float2half(v - __half2float(hv));
        }
    }
}

// ---------------------------------------------------------------------------
// Fused masked flash attention on MFMA (split fp16, swapped QK^T).
// Grid: 1024 blocks x 256 threads. Block = (bh, 32 q-rows); wave w = m-chunk.
// K-hi double-buffered in regs. launch_bounds(256,2): VGPR cap 128, no spills
// (R9 lesson: (256,4) squeezed to 64 VGPR -> scratch spills, FETCH 14->77MB).
// mode 0: write relu(out)+bias split fp16 in FRAG-LINEAR A layout (for qkv2).
// ---------------------------------------------------------------------------
__global__ __launch_bounds__(256, 2) void gat_attn(
    const __half* __restrict__ qhi, const __half* __restrict__ qlo,
    const __half* __restrict__ khi, const __half* __restrict__ klo,
    const __half* __restrict__ vthi, const __half* __restrict__ vtlo,
    const unsigned long long* __restrict__ adjp,
    const float* __restrict__ bias, float* __restrict__ out,
    __half* __restrict__ hhi, __half* __restrict__ hlo, const int mode)
{
    const int lid = (blockIdx.x & 7) * 128 + (blockIdx.x >> 3);
    const int bh = lid >> 6, qt = lid & 63;
    const int b = bh >> 2, h = bh & 3;
    const int tid = threadIdx.x;
    const int wave = tid >> 6;
    const int lane = tid & 63;
    const int lq = lane & 31;
    const int hh = lane >> 5;
    const int q0 = qt * 32;

    const size_t qkbase = (size_t)bh * 2048 * 64;

    // Q fragments (B-operand: col = lane&31 = q, k = 16*ks + 8*hh + e)
    half8 qfh[4], qfl[4];
    {
        const __half* qr_h = qhi + qkbase + (size_t)(q0 + lq) * 64 + 8 * hh;
        const __half* qr_l = qlo + qkbase + (size_t)(q0 + lq) * 64 + 8 * hh;
        #pragma unroll
        for (int ks = 0; ks < 4; ++ks) {
            qfh[ks] = *reinterpret_cast<const half8*>(qr_h + ks * 16);
            qfl[ks] = *reinterpret_cast<const half8*>(qr_l + ks * 16);
        }
    }

    f32x16 o0 = zero16(), o1 = zero16();
    float mrun = -1e30f, lrun = 0.f;

    const unsigned long long* __restrict__ wrow = adjp + (size_t)(b * 2048 + q0 + lq) * 32;
    const int mbase = wave * 512;
    const int klane = lq * 16 + 8 * hh;      // lane offset within a 2048-half K tile

    // preload K-hi tile 0
    half8 kA[4], kB[4];
    {
        const __half* kp = khi + ((size_t)(bh * 64) + (mbase >> 5)) * 2048 + klane;
        #pragma unroll
        for (int ks = 0; ks < 4; ++ks) kA[ks] = *reinterpret_cast<const half8*>(kp + ks * 512);
    }

    unsigned long long wm64 = 0;

    auto tile_body = [&](half8 (&khc)[4], half8 (&khn)[4], int tt) {
        const int mt = mbase + 32 * tt;

        if ((tt & 1) == 0) wm64 = wrow[mt >> 6];
        const unsigned int v32 = (unsigned int)(wm64 >> ((tt & 1) * 32));

        // K-lo loads for this tile (covered by the 8 kh-only MFMAs below)
        const __half* klp = klo + ((size_t)(bh * 64) + (mt >> 5)) * 2048 + klane;
        half8 klv[4];
        #pragma unroll
        for (int ks = 0; ks < 4; ++ks) klv[ks] = *reinterpret_cast<const half8*>(klp + ks * 512);

        // ---- scores S^T = K * Q^T: kh terms first (prefetched), kl last ----
        f32x16 st = zero16();
        __builtin_amdgcn_s_setprio(1);
        #pragma unroll
        for (int ks = 0; ks < 4; ++ks)
            st = __builtin_amdgcn_mfma_f32_32x32x16_f16(khc[ks], qfh[ks], st, 0, 0, 0);
        #pragma unroll
        for (int ks = 0; ks < 4; ++ks)
            st = __builtin_amdgcn_mfma_f32_32x32x16_f16(khc[ks], qfl[ks], st, 0, 0, 0);
        #pragma unroll
        for (int ks = 0; ks < 4; ++ks)
            st = __builtin_amdgcn_mfma_f32_32x32x16_f16(klv[ks], qfh[ks], st, 0, 0, 0);
        __builtin_amdgcn_s_setprio(0);

        // ---- prefetch K-hi for next tile (consumed next tile_body) ----
        {
            const int mtn = (tt < 15) ? mt + 32 : mbase;   // wrap: harmless re-read
            const __half* knp = khi + ((size_t)(bh * 64) + (mtn >> 5)) * 2048 + klane;
            #pragma unroll
            for (int ks = 0; ks < 4; ++ks) khn[ks] = *reinterpret_cast<const half8*>(knp + ks * 512);
        }

        // ---- V loads issued early (hide latency under softmax) ----
        const __half* vb_h = vthi + ((size_t)(bh * 128) + (mt >> 4)) * 1024 + klane;
        const __half* vb_l = vtlo + ((size_t)(bh * 128) + (mt >> 4)) * 1024 + klane;
        half8 va0h = *reinterpret_cast<const half8*>(vb_h);
        half8 vb0h = *reinterpret_cast<const half8*>(vb_h + 512);
        half8 va0l = *reinterpret_cast<const half8*>(vb_l);
        half8 vb0l = *reinterpret_cast<const half8*>(vb_l + 512);

        // ---- mask + online softmax ----
        const unsigned int w2 = v32 >> (4 * hh);
        const unsigned int bits = (w2 & 0xFu) | ((w2 >> 4) & 0xF0u)
                                | ((w2 >> 8) & 0xF00u) | ((w2 >> 12) & 0xF000u);
        float tv[16];
        #pragma unroll
        for (int i = 0; i < 16; ++i)
            tv[i] = ((bits >> i) & 1u) ? st[i] : -1e30f;
        // balanced max tree (max3-fusable)
        float a0 = fmaxf(fmaxf(tv[0], tv[1]), tv[2]);
        float a1 = fmaxf(fmaxf(tv[3], tv[4]), tv[5]);
        float a2 = fmaxf(fmaxf(tv[6], tv[7]), tv[8]);
        float a3 = fmaxf(fmaxf(tv[9], tv[10]), tv[11]);
        float a4 = fmaxf(fmaxf(tv[12], tv[13]), tv[14]);
        float pm = fmaxf(fmaxf(fmaxf(a0, a1), fmaxf(a2, a3)), fmaxf(a4, tv[15]));
        pm = fmaxf(pm, __shfl_xor(pm, 32, 64));
        if (!__all(pm <= mrun)) {
            float mnew = fmaxf(mrun, pm);
            float sf = __expf(mrun - mnew);
            mrun = mnew;
            lrun *= sf;
            o0 *= sf;
            o1 *= sf;
        }
        float e[16];
        #pragma unroll
        for (int i = 0; i < 16; ++i)
            e[i] = ((bits >> i) & 1u) ? __expf(tv[i] - mrun) : 0.f;
        float ps = (((e[0] + e[1]) + (e[2] + e[3])) + ((e[4] + e[5]) + (e[6] + e[7])))
                 + (((e[8] + e[9]) + (e[10] + e[11])) + ((e[12] + e[13]) + (e[14] + e[15])));
        ps += __shfl_xor(ps, 32, 64);
        lrun += ps;

        // ---- P -> split fp16 B-frags + PV ----
        half8 va1h, vb1h, va1l, vb1l;
        #pragma unroll
        for (int t2 = 0; t2 < 2; ++t2) {
            unsigned int Hp[4], Lp[4];
            #pragma unroll
            for (int p2 = 0; p2 < 4; ++p2) {
                float ea = e[8 * t2 + 2 * p2], eb = e[8 * t2 + 2 * p2 + 1];
                union { fp16x2 f; unsigned int u; } ch, cl;
                ch.f = __builtin_amdgcn_cvt_pkrtz(ea, eb);
                float fa = (float)ch.f[0], fb = (float)ch.f[1];
                cl.f = __builtin_amdgcn_cvt_pkrtz(ea - fa, eb - fb);
                Hp[p2] = ch.u; Lp[p2] = cl.u;
            }
            unsigned int hr1 = (unsigned)__shfl_xor((int)(hh ? Hp[0] : Hp[2]), 32, 64);
            unsigned int hr2 = (unsigned)__shfl_xor((int)(hh ? Hp[1] : Hp[3]), 32, 64);
            unsigned int lr1 = (unsigned)__shfl_xor((int)(hh ? Lp[0] : Lp[2]), 32, 64);
            unsigned int lr2 = (unsigned)__shfl_xor((int)(hh ? Lp[1] : Lp[3]), 32, 64);
            union { unsigned int u[4]; half8 hv; } Bh, Bl;
            Bh.u[0] = hh ? hr1 : Hp[0]; Bh.u[1] = hh ? hr2 : Hp[1];
            Bh.u[2] = hh ? Hp[2] : hr1; Bh.u[3] = hh ? Hp[3] : hr2;
            Bl.u[0] = hh ? lr1 : Lp[0]; Bl.u[1] = hh ? lr2 : Lp[1];
            Bl.u[2] = hh ? Lp[2] : lr1; Bl.u[3] = hh ? Lp[3] : lr2;

            if (t2 == 0) {
                va1h = *reinterpret_cast<const half8*>(vb_h + 1024);
                vb1h = *reinterpret_cast<const half8*>(vb_h + 1536);
                va1l = *reinterpret_cast<const half8*>(vb_l + 1024);
                vb1l = *reinterpret_cast<const half8*>(vb_l + 1536);
            }
            half8 vah  = t2 ? va1h : va0h;
            half8 val  = t2 ? va1l : va0l;
            half8 vbh2 = t2 ? vb1h : vb0h;
            half8 vbl2 = t2 ? vb1l : vb0l;

            __builtin_amdgcn_s_setprio(1);
            o0 = __builtin_amdgcn_mfma_f32_32x32x16_f16(vah, Bh.hv, o0, 0, 0, 0);
            o0 = __builtin_amdgcn_mfma_f32_32x32x16_f16(val, Bh.hv, o0, 0, 0, 0);
            o0 = __builtin_amdgcn_mfma_f32_32x32x16_f16(vah, Bl.hv, o0, 0, 0, 0);
            o1 = __builtin_amdgcn_mfma_f32_32x32x16_f16(vbh2, Bh.hv, o1, 0, 0, 0);
            o1 = __builtin_amdgcn_mfma_f32_32x32x16_f16(vbl2, Bh.hv, o1, 0, 0, 0);
            o1 = __builtin_amdgcn_mfma_f32_32x32x16_f16(vbh2, Bl.hv, o1, 0, 0, 0);
            __builtin_amdgcn_s_setprio(0);
        }
    };

    #pragma unroll 1
    for (int tt2 = 0; tt2 < 8; ++tt2) {
        tile_body(kA, kB, 2 * tt2);       // uses kA, prefetches into kB
        tile_body(kB, kA, 2 * tt2 + 1);   // uses kB, prefetches into kA
    }

    // ---- in-LDS merge of the 4 m-chunk partials ----
    __shared__ float OS[4][64][33];
    __shared__ float MS[4][32];
    __shared__ float LS[4][32];

    #pragma unroll
    for (int ct = 0; ct < 2; ++ct) {
        #pragma unroll
        for (int i = 0; i < 16; ++i) {
            int c = 32 * ct + (i & 3) + 8 * (i >> 2) + 4 * hh;
            OS[wave][c][lq] = ct ? o1[i] : o0[i];
        }
    }
    if (hh == 0) { MS[wave][lq] = mrun; LS[wave][lq] = lrun; }
    __syncthreads();

    const int q = tid >> 3, c8 = (tid & 7) * 8;
    float m0v = MS[0][q], m1v = MS[1][q], m2v = MS[2][q], m3v = MS[3][q];
    float M = fmaxf(fmaxf(m0v, m1v), fmaxf(m2v, m3v));
    float w0 = __expf(m0v - M), w1 = __expf(m1v - M), w2w = __expf(m2v - M), w3 = __expf(m3v - M);
    float L = LS[0][q] * w0 + LS[1][q] * w1 + LS[2][q] * w2w + LS[3][q] * w3;
    float inv = 1.f / (L + 1e-16f);
    float res[8];
    #pragma unroll
    for (int j = 0; j < 8; ++j) {
        int c = c8 + j;
        float o = OS[0][c][q] * w0 + OS[1][c][q] * w1 + OS[2][c][q] * w2w + OS[3][c][q] * w3;
        res[j] = o * inv + bias[h * 64 + c];
    }
    const int rowv = b * 2048 + q0 + q;      // global node row
    if (mode == 0) {
        // h in FRAG-LINEAR A layout: col K = h*64+c8 (8 contiguous halfs)
        union { __half h[8]; uint4 u; } sh, sl;
        #pragma unroll
        for (int j = 0; j < 8; ++j) {
            float val = fmaxf(res[j], 0.f);   // relu
            __half hv = __float2half(val);
            sh.h[j] = hv;
            sl.h[j] = __float2half(val - __half2float(hv));
        }
        const int K = h * 64 + c8;
        size_t dst = (size_t)(rowv >> 5) * 8192 + (size_t)(K >> 4) * 512
                   + (size_t)(rowv & 31) * 16 + (K & 15);
        *reinterpret_cast<uint4*>(&hhi[dst]) = sh.u;
        *reinterpret_cast<uint4*>(&hlo[dst]) = sl.u;
    } else {
        size_t oidx = (size_t)rowv * 256 + h * 64 + c8;
        *reinterpret_cast<float4*>(&out[oidx])     = make_float4(res[0], res[1], res[2], res[3]);
        *reinterpret_cast<float4*>(&out[oidx + 4]) = make_float4(res[4], res[5], res[6], res[7]);
    }
}

// ---------------------------------------------------------------------------
extern "C" void kernel_launch(void* const* d_in, const int* in_sizes, int n_in,
                              void* d_out, int out_size, void* d_ws, size_t ws_size,
                              hipStream_t stream) {
    const float* x   = (const float*)d_in[0];
    const int*   adj = (const int*)d_in[1];
    const float* Wq1 = (const float*)d_in[2];
    const float* Wk1 = (const float*)d_in[3];
    const float* Wv1 = (const float*)d_in[4];
    const float* b1  = (const float*)d_in[5];
    const float* Wq2 = (const float*)d_in[6];
    const float* Wk2 = (const float*)d_in[7];
    const float* Wv2 = (const float*)d_in[8];
    const float* b2  = (const float*)d_in[9];
    float* outp = (float*)d_out;

    // workspace layout (MB offsets), total 44MB
    char* ws = (char*)d_ws;
    unsigned long long* adjp = (unsigned long long*)ws;        //  0..2
    __half* xhi = (__half*)(ws + ( 2u << 20));                 //  2..6   (reused as hhi)
    __half* xlo = (__half*)(ws + ( 6u << 20));                 //  6..10  (reused as hlo)
    __half* wth = (__half*)(ws + (10u << 20));                 // 10..11 (768KB)
    __half* wtl = (__half*)(ws + (11u << 20));                 // 11..12
    __half* qhi = (__half*)(ws + (12u << 20));
    __half* qlo = (__half*)(ws + (16u << 20));
    __half* khi = (__half*)(ws + (20u << 20));
    __half* klo = (__half*)(ws + (24u << 20));
    __half* vthi= (__half*)(ws + (36u << 20));
    __half* vtlo= (__half*)(ws + (40u << 20));

    pack_adj<<<65536, 256, 0, stream>>>(adj, adjp);
    split_x<<<2048, 256, 0, stream>>>(x, xhi, xlo);
    split_w<<<dim3(16, 6), 256, 0, stream>>>(Wq1, Wk1, Wv1, Wq2, Wk2, Wv2, wth, wtl);

    qkv_gemm_mfma<<<dim3(128, 12), 256, 0, stream>>>(xhi, xlo, wth, wtl, 0,
                                                     qhi, qlo, khi, klo, vthi, vtlo);
    gat_attn<<<1024, 256, 0, stream>>>(qhi, qlo, khi, klo, vthi, vtlo, adjp, b1,
                                       outp, xhi, xlo, 0);

    qkv_gemm_mfma<<<dim3(128, 12), 256, 0, stream>>>(xhi, xlo, wth, wtl, 3,
                                                     qhi, qlo, khi, klo, vthi, vtlo);
    gat_attn<<<1024, 256, 0, stream>>>(qhi, qlo, khi, klo, vthi, vtlo, adjp, b2,
                                       outp, xhi, xlo, 1);
}